// Round 9
// baseline (121.730 us; speedup 1.0000x reference)
//
#include <hip/hip_runtime.h>

// AMPS chain kernel v9 — software-pipelined LDS reads (register rotation).
//
// v8 -> v9: the invariant ~40 µs across v3-v8 was per-step exposed ds_read
// latency (~120 cyc): every variant consumed LDS data in the same step it
// was loaded (compiler never pipelined it — VGPR_Count 44 proves no
// lookahead). v9 flattens each segment into a step stream over a 32-step
// LDS ring (4 bufs x 8 steps) and rotates 4 float4 registers: compute step
// s from rot[s&3], then issue the ds_read2 pair for step s+4 into the freed
// register. The wait before step-s fmacs is lgkmcnt(6) for a pair issued
// ~160 cyc earlier -> LDS latency fully hidden. Reads for chunk c+1's first
// half are issued during chunk c; WAITVM(4) at boundary c guarantees chunk
// c+1's global_load_lds landed (distance-2 HBM slack). Mask loads issue
// BEFORE the first stages so their register-wait (vmcnt(6)) doesn't drain
// the stage queue. Identity-fill for task-length mismatch runs at the
// boundary that readies chunk c+1, before any read targets it.

#define NPOS   1024
#define SEGLEN 64
#define MAXSEG 16
#define CH     8
#define NBUF   4
#define NTASK  8688                    // sum_{s=0}^{15} (1023 - 64 s)
#define NWAVE  (NTASK / 2)             // 4344
#define NBLOCK (NWAVE / 4)             // 1086
#define TRI_ELEMS (523776 * 32)

template<int l>
__device__ __forceinline__ float qb(float x) {
    constexpr int ctrl = l * 0x55;     // quad_perm broadcast lane l
    return __int_as_float(__builtin_amdgcn_update_dpp(
        __float_as_int(x), __float_as_int(x), ctrl, 0xF, 0xF, false));
}
template<int ctrl>
__device__ __forceinline__ float qperm(float x) {
    return __int_as_float(__builtin_amdgcn_update_dpp(
        __float_as_int(x), __float_as_int(x), ctrl, 0xF, 0xF, false));
}

__device__ __forceinline__ void gl_lds16(const float* g, float* l) {
    __builtin_amdgcn_global_load_lds(
        (const __attribute__((address_space(1))) void*)g,
        (__attribute__((address_space(3))) void*)l, 16, 0, 0);
}

// wait until <=N vmem ops outstanding (N<=15); lgkm/exp ignored (gfx9 enc)
#define WAITVM(N) __builtin_amdgcn_s_waitcnt((N) | 0x0F70)

__device__ __forceinline__ void decode_task(int id, int& s, int& n) {
    int base = 0, cnt = 1023;
    s = 0;
    while (id >= base + cnt) { base += cnt; s++; cnt -= SEGLEN; }
    n = 1022 - (id - base);            // long chains first within each class
}

__global__ __launch_bounds__(256, 4) void amps_seg(
        const float* __restrict__ data,   // (8, 1024)
        const float* __restrict__ tri,    // (523776, 4, 4, 2)
        float* __restrict__ segout)       // (1023, 16, 8, 4, 4) = P^T per seg
{
    const int tid  = threadIdx.x;
    const int wid  = tid >> 6;
    const int lane = tid & 63;
    const int w    = blockIdx.x * 4 + wid;        // wave 0..4343
    const int t    = lane >> 5;           // task half 0/1
    const int q    = lane & 31;
    const int b    = q >> 2;              // batch
    const int i    = q & 3;               // C row = M row loaded

    int sA, nA, sB, nB;
    decode_task(2 * w,     sA, nA);
    decode_task(2 * w + 1, sB, nB);
    const int g0A = sA * SEGLEN,            g0B = sB * SEGLEN;
    const int stepsA = min(SEGLEN, nA + 1 - g0A);
    const int stepsB = min(SEGLEN, nB + 1 - g0B);
    const int tstA = (nA * (nA + 1) / 2 + g0A) * 32;
    const int tstB = (nB * (nB + 1) / 2 + g0B) * 32;

    const int nchA = (stepsA + 7) >> 3;
    const int nchB = (stepsB + 7) >> 3;
    const int nch  = max(nchA, nchB);     // wave-uniform

    const int g0_my    = t ? g0B : g0A;
    const int steps_my = t ? stepsB : stepsA;
    const int chunkf   = steps_my >> 3;   // first tail chunk
    const int rem      = steps_my & 7;
    const int n_my     = t ? nB : nA;
    const int s_my     = t ? sB : sA;

    __shared__ float lds_all[4][2][NBUF * CH * 32];   // 4 waves x 2 tasks x 4KB
    float* __restrict__ ldsA = &lds_all[wid][0][0];
    float* __restrict__ ldsB = &lds_all[wid][1][0];
    float* __restrict__ fillbuf = t ? ldsB : ldsA;
    float* __restrict__ mybuf   = fillbuf + i * 8;    // row base folded in

    // ---- 1) mask loads FIRST (oldest in vmcnt queue) ----
    const float4* dp4 = (const float4*)(data + b * NPOS + g0_my + i * 16);
    float4 f0 = dp4[0], f1 = dp4[1], f2 = dp4[2], f3 = dp4[3];

    // ---- 2) stages for chunks 0..2 ----
    auto stageA = [&](int c) {
        int off = min(tstA + c * 256 + lane * 4, TRI_ELEMS - 4);
        gl_lds16(tri + off, ldsA + (c & (NBUF - 1)) * 256);
    };
    auto stageB = [&](int c) {
        int off = min(tstB + c * 256 + lane * 4, TRI_ELEMS - 4);
        gl_lds16(tri + off, ldsB + (c & (NBUF - 1)) * 256);
    };
    stageA(0); stageB(0);
    stageA(1); stageB(1);
    stageA(2); stageB(2);

    // ---- 3) build per-lane 64-bit sel mask (compiler waits vmcnt(6):
    //          mask loads retire, stages stay in flight) ----
    unsigned m0, m1;
    {
        unsigned piece = 0;
        piece |= (f0.x != 1.0f) ? 1u : 0;        piece |= (f0.y != 1.0f) ? 2u : 0;
        piece |= (f0.z != 1.0f) ? 4u : 0;        piece |= (f0.w != 1.0f) ? 8u : 0;
        piece |= (f1.x != 1.0f) ? 0x10u : 0;     piece |= (f1.y != 1.0f) ? 0x20u : 0;
        piece |= (f1.z != 1.0f) ? 0x40u : 0;     piece |= (f1.w != 1.0f) ? 0x80u : 0;
        piece |= (f2.x != 1.0f) ? 0x100u : 0;    piece |= (f2.y != 1.0f) ? 0x200u : 0;
        piece |= (f2.z != 1.0f) ? 0x400u : 0;    piece |= (f2.w != 1.0f) ? 0x800u : 0;
        piece |= (f3.x != 1.0f) ? 0x1000u : 0;   piece |= (f3.y != 1.0f) ? 0x2000u : 0;
        piece |= (f3.z != 1.0f) ? 0x4000u : 0;   piece |= (f3.w != 1.0f) ? 0x8000u : 0;
        const int sb = t * 32 + b * 4;
        m0 = (unsigned)__shfl((int)piece, sb + 0)
           | ((unsigned)__shfl((int)piece, sb + 1) << 16);
        m1 = (unsigned)__shfl((int)piece, sb + 2)
           | ((unsigned)__shfl((int)piece, sb + 3) << 16);
    }
    auto bits_of = [&](int c) -> unsigned {
        unsigned word = (c < 4) ? m0 : m1;
        return (word >> ((c & 3) * 8)) & 0xFFu;
    };

    const float idval = ((q >> 3) == ((q >> 1) & 3)) ? 1.0f : 0.0f;
    auto fill = [&](int cc) {                 // identity-fill tail of chunk cc
        const int mstart = (cc == chunkf) ? rem : 0;
        float* bp = fillbuf + (cc & (NBUF - 1)) * 256 + q;
        for (int mm = mstart; mm < CH; mm++) bp[mm * 32] = idval;
    };

    // ---- 4) chunk 0 ready; fill if needed; preload steps 0..3 ----
    WAITVM(4);                                // chunk 0 landed; 1,2 in flight

    if (chunkf == 0) fill(0);

    float c0 = (i == 0) ? 1.0f : 0.0f;        // C row i of identity
    float c1 = (i == 1) ? 1.0f : 0.0f;
    float c2 = (i == 2) ? 1.0f : 0.0f;
    float c3 = (i == 3) ? 1.0f : 0.0f;

    float4 rot[4];
    auto rd = [&](int cc, int mm, unsigned bits, float4& dst) {
        const float* p = mybuf + (cc & (NBUF - 1)) * 256 + mm * 32
                       + ((bits >> mm) & 1u);
        dst.x = p[0]; dst.y = p[2]; dst.z = p[4]; dst.w = p[6];  // M[i][0..3]
    };
    auto fmas = [&](const float4& a) {
        // n_j = sum_k qb<k>(a_j) * c_k — DPP in src0, folds to v_fmac_dpp
        float n0 = qb<0>(a.x) * c0;
        n0 = fmaf(qb<1>(a.x), c1, n0);
        n0 = fmaf(qb<2>(a.x), c2, n0);
        n0 = fmaf(qb<3>(a.x), c3, n0);
        float n1 = qb<0>(a.y) * c0;
        n1 = fmaf(qb<1>(a.y), c1, n1);
        n1 = fmaf(qb<2>(a.y), c2, n1);
        n1 = fmaf(qb<3>(a.y), c3, n1);
        float n2 = qb<0>(a.z) * c0;
        n2 = fmaf(qb<1>(a.z), c1, n2);
        n2 = fmaf(qb<2>(a.z), c2, n2);
        n2 = fmaf(qb<3>(a.z), c3, n2);
        float n3 = qb<0>(a.w) * c0;
        n3 = fmaf(qb<1>(a.w), c1, n3);
        n3 = fmaf(qb<2>(a.w), c2, n3);
        n3 = fmaf(qb<3>(a.w), c3, n3);
        c0 = n0; c1 = n1; c2 = n2; c3 = n3;
    };

    unsigned bits_cur = bits_of(0);
    rd(0, 0, bits_cur, rot[0]);
    rd(0, 1, bits_cur, rot[1]);
    rd(0, 2, bits_cur, rot[2]);
    rd(0, 3, bits_cur, rot[3]);

    // ---- 5) main loop: one chunk (8 steps) per iteration ----
    for (int c = 0; c < nch; c++) {
        stageA(c + 3); stageB(c + 3);          // slot (c-1)&3: consumed
        WAITVM(4);                             // chunk c+1 landed
        if (c + 1 >= chunkf && c + 1 < nch) fill(c + 1);
        const unsigned bits_nxt = bits_of(c + 1);

        // compute step, then reuse its rot slot for step+4 (distance 4)
        fmas(rot[0]); rd(c,     4, bits_cur, rot[0]);
        fmas(rot[1]); rd(c,     5, bits_cur, rot[1]);
        fmas(rot[2]); rd(c,     6, bits_cur, rot[2]);
        fmas(rot[3]); rd(c,     7, bits_cur, rot[3]);
        fmas(rot[0]); rd(c + 1, 0, bits_nxt, rot[0]);
        fmas(rot[1]); rd(c + 1, 1, bits_nxt, rot[1]);
        fmas(rot[2]); rd(c + 1, 2, bits_nxt, rot[2]);
        fmas(rot[3]); rd(c + 1, 3, bits_nxt, rot[3]);

        bits_cur = bits_nxt;
    }

    // store P^T: segout[.. + j*4 + i] = P[i][j] = c_j
    const size_t o = (((size_t)n_my * MAXSEG + s_my) * 8 + b) * 16 + i;
    segout[o +  0] = c0;
    segout[o +  4] = c1;
    segout[o +  8] = c2;
    segout[o + 12] = c3;
}

__global__ __launch_bounds__(256) void amps_combine(
        const float* __restrict__ segout, // (1023, 16, 8, 16) P^T
        const float* __restrict__ diag,   // (1024, 4, 2)
        const float* __restrict__ data,   // (8, 1024)
        float* __restrict__ out)          // (8) — pre-zeroed by memset
{
    const int tid = threadIdx.x;
    const int q   = tid >> 5;             // chain slot in block, 0..7
    const int sub = tid & 31;
    const int b   = sub >> 2;
    const int r   = sub & 3;
    const int n   = blockIdx.x * 8 + q;   // 0..1023 (1023 invalid)

    __shared__ float sh[64];

    float res = 0.0f;
    if (n < NPOS - 1) {
        const int nseg = n / SEGLEN + 1;
        const float* basep = segout + (size_t)n * (MAXSEG * 128)
                           + b * 16 + r * 4;
        float v = (r == 0) ? 1.0f : 0.0f;
        #pragma unroll
        for (int s2 = 0; s2 < MAXSEG; s2++) {
            if (s2 >= nseg) break;
            float4 P = *(const float4*)(basep + s2 * 128);
            float acc = qb<0>(v) * P.x;
            acc = fmaf(qb<1>(v), P.y, acc);
            acc = fmaf(qb<2>(v), P.z, acc);
            v   = fmaf(qb<3>(v), P.w, acc);
        }

        const int pos = n + 1;
        const float* dg = diag + pos * 8 + r * 2;
        float o0 = v * dg[0];
        float o1 = v * dg[1];
        o0 += qperm<0xB1>(o0); o0 += qperm<0x4E>(o0);   // quad sum over r
        o1 += qperm<0xB1>(o1); o1 += qperm<0x4E>(o1);
        float mx  = fmaxf(o0, o1);
        float lse = mx + __logf(__expf(o0 - mx) + __expf(o1 - mx));
        float dsel = data[b * NPOS + pos];
        res = ((dsel == 1.0f) ? o0 : o1) - lse;
    }
    if (r == 0) sh[q * 8 + b] = res;
    __syncthreads();
    if (tid < 8) {
        float ssum = 0.0f;
        #pragma unroll
        for (int qq = 0; qq < 8; qq++) ssum += sh[qq * 8 + tid];
        if (blockIdx.x == 0) {
            float o0 = diag[0], o1 = diag[1];
            float mx  = fmaxf(o0, o1);
            float lse = mx + __logf(__expf(o0 - mx) + __expf(o1 - mx));
            float d0  = data[tid * NPOS];
            ssum += ((d0 == 1.0f) ? o0 : o1) - lse;
        }
        atomicAdd(out + tid, ssum);
    }
}

extern "C" void kernel_launch(void* const* d_in, const int* in_sizes, int n_in,
                              void* d_out, int out_size, void* d_ws, size_t ws_size,
                              hipStream_t stream)
{
    const float* data = (const float*)d_in[0];   // (8, 1024)
    const float* tri  = (const float*)d_in[1];   // (523776, 4, 4, 2)
    const float* diag = (const float*)d_in[2];   // (1024, 4, 2)

    float* segout = (float*)d_ws;                // 1023*16*8*16*4 = 8,380,416 B
    float* out    = (float*)d_out;               // 8 floats

    hipMemsetAsync(d_out, 0, 8 * sizeof(float), stream);
    amps_seg<<<dim3(NBLOCK), dim3(256), 0, stream>>>(data, tri, segout);
    amps_combine<<<dim3(128), dim3(256), 0, stream>>>(segout, diag, data, out);
}